// Round 6
// baseline (851.184 us; speedup 1.0000x reference)
//
#include <hip/hip_runtime.h>
#include <hip/hip_bf16.h>

#define N_NODES 50000
#define N_EDGES 800000
#define NB1 400       // k1 bucketing blocks
#define CH  2000      // edges per k1 block (NB1*CH == N_EDGES)
#define NBKT 391      // buckets = node>>7 (128 nodes per bucket)
#define CAP 4096      // slots per bucket (mean ~2046, >40 sigma headroom)

typedef unsigned short ushort_t;
typedef unsigned long long u64;
typedef __attribute__((ext_vector_type(8))) short bf16x8;
typedef __attribute__((ext_vector_type(4))) float f32x4;

// ---------------- workspace layout (4-byte word offsets) ----------------
constexpr int GCUR_O  = 0;           // uint[782*16] cursors, 64B-strided (col: b*16, row: (391+b)*16)
constexpr int DIS_O   = 12544;       // float[50048]
constexpr size_t CSLOT_O = 62592;    // u64[391*4096]  col buckets: (w | col7<<16 | row16)
constexpr size_t RSLOT_O = 3265664;  // uint[391*4096] row buckets: (w&~127 | row7)
constexpr size_t XS_O    = 4867200;  // uint[50000*32] xs = dis*x, word q = feats (q, q+32)
constexpr size_t T1S_O   = 6467200;  // uint[50000*32] dis*tx1,   word q = feats (q, q+32)
constexpr size_t ABUF_O  = 8067200;  // uint[50048*96] A=[x|tx1|tx2], word q = feats (2q, 2q+1)
constexpr size_t PBUF_O  = 12871808; // ushort[24576] packed B
// total ~12.9M words = 51.5 MB

__device__ __forceinline__ ushort_t f32_to_bf16(float f) {
    unsigned u = __float_as_uint(f);
    u += 0x7fffu + ((u >> 16) & 1u);   // round-to-nearest-even
    return (ushort_t)(u >> 16);
}
__device__ __forceinline__ float bflo(unsigned u) { return __uint_as_float(u << 16); }
__device__ __forceinline__ float bfhi(unsigned u) { return __uint_as_float(u & 0xffff0000u); }
__device__ __forceinline__ unsigned packbf2(float a, float b) {
    return (unsigned)f32_to_bf16(a) | ((unsigned)f32_to_bf16(b) << 16);
}
__device__ __forceinline__ float fsigmoid(float x) { return 1.f / (1.f + __expf(-x)); }
__device__ __forceinline__ float ftanh(float x) {
    x = fminf(15.f, fmaxf(-15.f, x));
    float e = __expf(2.f * x);
    return (e - 1.f) / (e + 1.f);
}

// ---- k1: dual bucketing (col for prop, row for deg) + packB. No sort needed. ----
__global__ __launch_bounds__(512) void k1(
    const int* __restrict__ ei, const float* __restrict__ ew,
    const float* __restrict__ Wxz, const float* __restrict__ Wxh,
    unsigned* __restrict__ gcur, u64* __restrict__ cslot,
    unsigned* __restrict__ rslot, ushort_t* __restrict__ pbuf) {
    int bid = blockIdx.x, t = threadIdx.x;
    if (bid < NB1) {
        __shared__ unsigned colbuf[CH], rowbuf[CH];
        __shared__ unsigned hc[NBKT], hr[NBKT], bc[NBKT], br[NBKT];
        if (t < NBKT) { hc[t] = 0; hr[t] = 0; }
        __syncthreads();
        int e0 = bid * CH;
        for (int i = t; i < CH; i += 512) {
            unsigned r = (unsigned)ei[e0 + i];
            unsigned c = (unsigned)ei[N_EDGES + e0 + i];
            rowbuf[i] = r;
            colbuf[i] = c;
            atomicAdd(&hc[c >> 7], 1u);
            atomicAdd(&hr[r >> 7], 1u);
        }
        __syncthreads();
        if (t < NBKT) {
            bc[t] = atomicAdd(&gcur[t * 16], hc[t]);           // padded: 1 cursor/line
            br[t] = atomicAdd(&gcur[(NBKT + t) * 16], hr[t]);
        }
        __syncthreads();
        if (t < NBKT) { hc[t] = 0; hr[t] = 0; }                // reuse as local cursors
        __syncthreads();
        for (int i = t; i < CH; i += 512) {
            unsigned c = colbuf[i];
            unsigned r = rowbuf[i];
            unsigned w = __float_as_uint(ew[e0 + i]);
            unsigned dc = c >> 7;
            unsigned pc = bc[dc] + atomicAdd(&hc[dc], 1u);
            if (pc < CAP)
                cslot[(size_t)dc * CAP + pc] = ((u64)w << 32) | ((c & 127u) << 16) | (r & 0xFFFFu);
            unsigned dr = r >> 7;
            unsigned pr = br[dr] + atomicAdd(&hr[dr], 1u);
            if (pr < CAP)
                rslot[(size_t)dr * CAP + pr] = (w & 0xFFFFFF80u) | (r & 127u);
        }
    } else {                                     // pack B into MFMA fragment order
        for (int idx = t; idx < 24576; idx += 512) {
            int k = idx >> 7, n = idx & 127;
            float v = (n < 64) ? Wxz[k * 64 + n] : Wxh[k * 64 + (n - 64)];
            int c = n >> 4, s = k >> 5, l = (((k >> 3) & 3) << 4) | (n & 15), j = k & 7;
            pbuf[((c * 6 + s) * 64 + l) * 8 + j] = f32_to_bf16(v);
        }
    }
}

// ---- k2: deg (LDS fadd from row bucket) -> dis, x-cast, xs = dis*x ----
__global__ __launch_bounds__(512) void k2(
    const float* __restrict__ x, const unsigned* __restrict__ gcur,
    const unsigned* __restrict__ rslot, float* __restrict__ dis,
    unsigned* __restrict__ abuf, unsigned* __restrict__ xs) {
    int bid = blockIdx.x, t = threadIdx.x;
    __shared__ float facc[128];
    if (t < 128) facc[t] = 0.f;
    __syncthreads();
    unsigned szr = min(gcur[(NBKT + bid) * 16], (unsigned)CAP);
    const unsigned* rs = rslot + (size_t)bid * CAP;
    for (unsigned i = t; i < szr; i += 512)
        atomicAdd(&facc[rs[i] & 127u], __uint_as_float(rs[i] & 0xFFFFFF80u));
    __syncthreads();
    if (t < 128) {
        float d = facc[t];
        float r = d > 0.f ? rsqrtf(d) : 0.f;
        facc[t] = r;
        int n = bid * 128 + t;
        if (n < N_NODES) dis[n] = r;
    }
    __syncthreads();
    for (int idx = t; idx < 128 * 32; idx += 512) {
        int nl = idx >> 5, q = idx & 31;
        int n = bid * 128 + nl;
        if (n < N_NODES) {
            float r = facc[nl];
            float2 xp = ((const float2*)x)[n * 32 + q];          // feats 2q, 2q+1
            abuf[n * 96 + q] = packbf2(xp.x, xp.y);
            float xa = x[n * 64 + q], xb = x[n * 64 + q + 32];   // feats q, q+32
            xs[n * 32 + q] = packbf2(r * xa, r * xb);
        }
    }
}

// ---- k_prop: scatter-accumulate into LDS tile (sort-free propagation) ----
// tile[c][f] += w * src[row][f]  over this bucket's edges (ds_add_f32, commutative)
// mode 0: tx1 = -dis*tile -> abuf[32..63]; t1s = -dis^2*tile
// mode 1: tx2 = -2*dis*tile - x -> abuf[64..95]
__global__ __launch_bounds__(512) void k_prop(
    const unsigned* __restrict__ gcur, const u64* __restrict__ cslot,
    const unsigned* __restrict__ src, const float* __restrict__ dis,
    const float* __restrict__ x, unsigned* __restrict__ abuf,
    unsigned* __restrict__ t1s, int mode) {
    __shared__ float tile[128 * 64];   // 32 KB
    int bid = blockIdx.x, t = threadIdx.x;
    for (int i = t; i < 8192; i += 512) tile[i] = 0.f;
    __syncthreads();
    unsigned sz = min(gcur[bid * 16], (unsigned)CAP);
    const u64* cs = cslot + (size_t)bid * CAP;
    int lane = t & 63, wv = t >> 6;
    int h = lane >> 5, q = lane & 31;
    unsigned i0 = wv * 8 + h * 4;                 // half-wave handles 4 consecutive edges
    unsigned szf = sz & ~63u;
    for (unsigned i = i0; i < szf; i += 64) {     // 64 edges per block-iter
        ulonglong2 pA = *(const ulonglong2*)(cs + i);
        ulonglong2 pB = *(const ulonglong2*)(cs + i + 2);
#pragma unroll
        for (int j = 0; j < 4; ++j) {
            u64 p = (j == 0) ? pA.x : (j == 1) ? pA.y : (j == 2) ? pB.x : pB.y;
            unsigned lo = (unsigned)p;
            float w = __uint_as_float((unsigned)(p >> 32));
            unsigned c = (lo >> 16) & 127u;
            unsigned r = lo & 0xFFFFu;
            unsigned u = src[r * 32 + q];         // feats (q, q+32) of source row
            atomicAdd(&tile[c * 64 + q], w * bflo(u));
            atomicAdd(&tile[c * 64 + q + 32], w * bfhi(u));
        }
    }
    for (unsigned e = szf + (unsigned)(wv * 2 + h); e < sz; e += 16) {  // tail
        u64 p = cs[e];
        unsigned lo = (unsigned)p;
        float w = __uint_as_float((unsigned)(p >> 32));
        unsigned c = (lo >> 16) & 127u;
        unsigned r = lo & 0xFFFFu;
        unsigned u = src[r * 32 + q];
        atomicAdd(&tile[c * 64 + q], w * bflo(u));
        atomicAdd(&tile[c * 64 + q + 32], w * bfhi(u));
    }
    __syncthreads();
    for (int idx = t; idx < 128 * 32; idx += 512) {
        int nl = idx >> 5, q2 = idx & 31;
        int n = bid * 128 + nl;
        if (n < N_NODES) {
            float di = dis[n];
            float s0 = tile[nl * 64 + 2 * q2], s1 = tile[nl * 64 + 2 * q2 + 1];
            if (mode == 0) {
                abuf[n * 96 + 32 + q2] = packbf2(-di * s0, -di * s1);
                float u0 = tile[nl * 64 + q2], u1 = tile[nl * 64 + q2 + 32];
                float d2 = -di * di;
                t1s[n * 32 + q2] = packbf2(d2 * u0, d2 * u1);
            } else {
                float2 xp = ((const float2*)x)[n * 32 + q2];
                abuf[n * 96 + 64 + q2] = packbf2(-2.f * di * s0 - xp.x,
                                                 -2.f * di * s1 - xp.y);
            }
        }
    }
}

// ---- MFMA GEMM [50048x192]@[192x128] + GRU combine + head ----
__global__ __launch_bounds__(256) void k_gemm(
    const ushort_t* __restrict__ ab, const ushort_t* __restrict__ pbuf,
    const float* __restrict__ bxz, const float* __restrict__ bhz,
    const float* __restrict__ bxh, const float* __restrict__ bhh,
    const float* __restrict__ Wlin, const float* __restrict__ blin,
    float2* __restrict__ out) {
    __shared__ ushort_t bsh[24576];
    int tid = threadIdx.x;
    {
        uint4* s4 = (uint4*)bsh;
        const uint4* g4 = (const uint4*)pbuf;
        for (int i = tid; i < 3072; i += 256) s4[i] = g4[i];
    }
    __syncthreads();

    int wave = tid >> 6, lane = tid & 63;
    int quad = lane >> 4, m = lane & 15;
    int arow = blockIdx.x * 64 + wave * 16 + m;
    const ushort_t* ap = ab + (size_t)arow * 192 + quad * 8;

    f32x4 acc[8];
#pragma unroll
    for (int c = 0; c < 8; ++c) acc[c] = (f32x4){0.f, 0.f, 0.f, 0.f};
#pragma unroll
    for (int s = 0; s < 6; ++s) {
        bf16x8 af = *(const bf16x8*)(ap + s * 32);
#pragma unroll
        for (int c = 0; c < 8; ++c) {
            bf16x8 bfr = *(const bf16x8*)(bsh + ((c * 6 + s) * 64 + lane) * 8);
            acc[c] = __builtin_amdgcn_mfma_f32_16x16x32_bf16(af, bfr, acc[c], 0, 0, 0);
        }
    }
    float bzv[4], bhv[4], wl0[4], wl1[4];
#pragma unroll
    for (int c = 0; c < 4; ++c) {
        int col = c * 16 + m;
        bzv[c] = bxz[col] + bhz[col];
        bhv[c] = bxh[col] + bhh[col];
        wl0[c] = Wlin[2 * col];
        wl1[c] = Wlin[2 * col + 1];
    }
    float bl0 = blin[0], bl1 = blin[1];
#pragma unroll
    for (int i = 0; i < 4; ++i) {
        float p0 = 0.f, p1 = 0.f;
#pragma unroll
        for (int c = 0; c < 4; ++c) {
            float z  = fsigmoid(acc[c][i] + bzv[c]);
            float ht = ftanh(acc[c + 4][i] + bhv[c]);
            float t  = ftanh((1.f - z) * ht);
            p0 += t * wl0[c];
            p1 += t * wl1[c];
        }
        for (int o = 1; o <= 8; o <<= 1) {
            p0 += __shfl_xor(p0, o, 64);
            p1 += __shfl_xor(p1, o, 64);
        }
        int g = blockIdx.x * 64 + wave * 16 + quad * 4 + i;
        if (m == 0 && g < N_NODES)
            out[g] = make_float2(fsigmoid(p0 + bl0), fsigmoid(p1 + bl1));
    }
}

extern "C" void kernel_launch(void* const* d_in, const int* in_sizes, int n_in,
                              void* d_out, int out_size, void* d_ws, size_t ws_size,
                              hipStream_t stream) {
    const float* x    = (const float*)d_in[0];
    const int*   ei   = (const int*)d_in[1];
    const float* ew   = (const float*)d_in[2];
    const float* Wxz  = (const float*)d_in[3];
    const float* bxz  = (const float*)d_in[4];
    const float* bhz  = (const float*)d_in[6];
    const float* Wxh  = (const float*)d_in[11];
    const float* bxh  = (const float*)d_in[12];
    const float* bhh  = (const float*)d_in[14];
    const float* Wlin = (const float*)d_in[15];
    const float* blin = (const float*)d_in[16];

    float*    ws    = (float*)d_ws;
    unsigned* gcur  = (unsigned*)(ws + GCUR_O);
    float*    dis   = ws + DIS_O;
    u64*      cslot = (u64*)(ws + CSLOT_O);
    unsigned* rslot = (unsigned*)(ws + RSLOT_O);
    unsigned* xs    = (unsigned*)(ws + XS_O);
    unsigned* t1s   = (unsigned*)(ws + T1S_O);
    unsigned* abuf  = (unsigned*)(ws + ABUF_O);
    ushort_t* pbuf  = (ushort_t*)(ws + PBUF_O);

    hipMemsetAsync(d_ws, 0, (size_t)(782 * 16) * 4, stream);   // padded cursors only

    k1<<<NB1 + 1, 512, 0, stream>>>(ei, ew, Wxz, Wxh, gcur, cslot, rslot, pbuf);
    k2<<<NBKT, 512, 0, stream>>>(x, gcur, rslot, dis, abuf, xs);
    k_prop<<<NBKT, 512, 0, stream>>>(gcur, cslot, xs, dis, x, abuf, t1s, 0);
    k_prop<<<NBKT, 512, 0, stream>>>(gcur, cslot, t1s, dis, x, abuf, t1s, 1);
    k_gemm<<<782, 256, 0, stream>>>((const ushort_t*)abuf, pbuf, bxz, bhz, bxh, bhh,
                                    Wlin, blin, (float2*)d_out);
}

// Round 8
// 214.167 us; speedup vs baseline: 3.9744x; 3.9744x over previous
//
#include <hip/hip_runtime.h>
#include <hip/hip_bf16.h>

#define N_NODES 50000
#define N_EDGES 800000
#define NB1 400       // k1 bucketing blocks
#define CH  2000      // edges per k1 block (NB1*CH == N_EDGES)
#define NBKT 196      // MSD buckets = key>>8
#define CAP 8192      // slots per bucket (mean ~4082, +64 sigma headroom)
#define SORT_MAX 6144 // LDS sort capacity per bucket (+32 sigma)

typedef unsigned short ushort_t;
typedef unsigned long long u64;
typedef __attribute__((ext_vector_type(8))) short bf16x8;
typedef __attribute__((ext_vector_type(4))) float f32x4;

// ---------------- workspace layout (4-byte word offsets) ----------------
constexpr int GCUR_O  = 0;           // uint[512]: [0,196) col cursors, [256,452) row cursors
constexpr int DIS_O   = 512;         // float[50000]
constexpr int OFF_O   = 50512;       // int[50001]
constexpr int CSLOT_O = 100544;      // u64[196*8192] col buckets (w | col8 | row16)
constexpr int RSLOT_O = 3311808;     // uint[196*8192] row buckets (w24 | row8); T1S after k2
constexpr int RW_O    = 4917440;     // u64[800000] CSR payload (w | row)
constexpr int ABUF_O  = 6517440;     // uint[50000*96] A=[x|tx1|tx2] bf16x2
constexpr int PBUF_O  = 11317440;    // ushort[24576] packed B
constexpr int XS_O    = 11329728;    // uint[50000*32] xs = dis*x  (OWN region — round-7 race fix:
                                     // xs may NOT alias cslot when k2 phases run in separate blocks)
constexpr int T1S_O   = RSLOT_O;     // uint[50000*32] dis*tx1 (safe: rslot's last read is in k2,
                                     // t1s first written by k_prop after k2 completes)
// total ~12.93M words = 51.7 MB (ws is 256 MiB)

__device__ __forceinline__ ushort_t f32_to_bf16(float f) {
    unsigned u = __float_as_uint(f);
    u += 0x7fffu + ((u >> 16) & 1u);   // round-to-nearest-even
    return (ushort_t)(u >> 16);
}
__device__ __forceinline__ float bflo(unsigned u) { return __uint_as_float(u << 16); }
__device__ __forceinline__ float bfhi(unsigned u) { return __uint_as_float(u & 0xffff0000u); }
__device__ __forceinline__ unsigned packbf2(float a, float b) {
    return (unsigned)f32_to_bf16(a) | ((unsigned)f32_to_bf16(b) << 16);
}
__device__ __forceinline__ float fsigmoid(float x) { return 1.f / (1.f + __expf(-x)); }
__device__ __forceinline__ float ftanh(float x) {
    x = fminf(15.f, fmaxf(-15.f, x));
    float e = __expf(2.f * x);
    return (e - 1.f) / (e + 1.f);
}

// ---- k1: dual MSD bucketing (col for CSR w/ full payload, row for deg) ----
__global__ __launch_bounds__(512) void k1(
    const int* __restrict__ ei, const float* __restrict__ ew,
    const float* __restrict__ x, const float* __restrict__ Wxz,
    const float* __restrict__ Wxh, unsigned* __restrict__ gcur,
    u64* __restrict__ cslot, unsigned* __restrict__ rslot,
    unsigned* __restrict__ abuf, ushort_t* __restrict__ pbuf) {
    int bid = blockIdx.x, t = threadIdx.x;
    if (bid < NB1) {
        __shared__ unsigned colbuf[CH], rowbuf[CH];
        __shared__ unsigned hc[256], hr[256], bc[256], br[256];
        if (t < 256) { hc[t] = 0; hr[t] = 0; }
        __syncthreads();
        int e0 = bid * CH;
        for (int i = t; i < CH; i += 512) {
            unsigned r = (unsigned)ei[e0 + i];
            unsigned c = (unsigned)ei[N_EDGES + e0 + i];
            rowbuf[i] = r;
            colbuf[i] = c;
            atomicAdd(&hc[c >> 8], 1u);
            atomicAdd(&hr[r >> 8], 1u);
        }
        __syncthreads();
        if (t < NBKT) {
            bc[t] = atomicAdd(&gcur[t], hc[t]);
            br[t] = atomicAdd(&gcur[256 + t], hr[t]);
        }
        __syncthreads();
        if (t < 256) { hc[t] = 0; hr[t] = 0; }   // reuse as local cursors
        __syncthreads();
        for (int i = t; i < CH; i += 512) {
            unsigned c = colbuf[i];
            unsigned r = rowbuf[i];
            unsigned w = __float_as_uint(ew[e0 + i]);
            unsigned dc = c >> 8;
            unsigned pc = bc[dc] + atomicAdd(&hc[dc], 1u);
            if (pc < CAP)
                cslot[dc * CAP + pc] = ((u64)w << 32) | ((c & 255u) << 16) | (r & 0xFFFFu);
            unsigned dr = r >> 8;
            unsigned pr = br[dr] + atomicAdd(&hr[dr], 1u);
            if (pr < CAP) rslot[dr * CAP + pr] = (w & 0xFFFFFF00u) | (r & 255u);
        }
    } else if (bid < NB1 + 98) {                 // plain-x bf16 cast into A cols [0,64)
        int n0 = (bid - NB1) * 512;
        for (int idx = t; idx < 512 * 32; idx += 512) {
            int n = n0 + (idx >> 5);
            if (n < N_NODES) {
                int q = idx & 31;
                float2 xv = ((const float2*)x)[n * 32 + q];
                abuf[n * 96 + q] = packbf2(xv.x, xv.y);
            }
        }
    } else {                                     // pack B into MFMA fragment order
        for (int idx = t; idx < 24576; idx += 512) {
            int k = idx >> 7, n = idx & 127;
            float v = (n < 64) ? Wxz[k * 64 + n] : Wxh[k * 64 + (n - 64)];
            int c = n >> 4, s = k >> 5, l = (((k >> 3) & 3) << 4) | (n & 15), j = k & 7;
            pbuf[((c * 6 + s) * 64 + l) * 8 + j] = f32_to_bf16(v);
        }
    }
}

// ---- k2: blocks [0,196): per-bucket LDS sort -> off + direct-scatter rw
//          blocks [196,392): deg (LDS fadd) -> dis, xs = dis*x   (independent phases)
__global__ __launch_bounds__(512) void k2(
    const float* __restrict__ x, const unsigned* __restrict__ gcur,
    const u64* __restrict__ cslot, const unsigned* __restrict__ rslot,
    float* __restrict__ dis, int* __restrict__ off,
    u64* __restrict__ rw, unsigned* __restrict__ xs) {
    int bid = blockIdx.x, t = threadIdx.x;
    __shared__ unsigned rawA[SORT_MAX], rawB[SORT_MAX];
    __shared__ unsigned hist[256], hsc[256], cur[256], gs[256];
    __shared__ float facc[256];

    if (bid < NBKT) {
        // ---- phase A: sort col bucket bid by col&255 -> off + (row,w) CSR ----
        if (t < 256) {
            gs[t] = (t < NBKT) ? gcur[t] : 0u;
            hist[t] = 0;
        }
        __syncthreads();
        for (int o = 1; o < 256; o <<= 1) {          // inclusive scan of bucket sizes
            unsigned v = (t < 256 && t >= o) ? gs[t - o] : 0u;
            __syncthreads();
            if (t < 256) gs[t] += v;
            __syncthreads();
        }
        unsigned szb = gcur[bid];
        unsigned sz = min(szb, (unsigned)SORT_MAX);
        unsigned base = gs[bid] - szb;               // exclusive prefix
        for (unsigned i = t; i < sz; i += 512) {
            u64 v = cslot[bid * CAP + i];
            unsigned lo = (unsigned)v;
            rawA[i] = lo;
            rawB[i] = (unsigned)(v >> 32);
            atomicAdd(&hist[(lo >> 16) & 255u], 1u);
        }
        __syncthreads();
        unsigned h0 = (t < 256) ? hist[t] : 0u;
        if (t < 256) hsc[t] = h0;
        __syncthreads();
        for (int o = 1; o < 256; o <<= 1) {          // inclusive scan of digit hist
            unsigned v = (t < 256 && t >= o) ? hsc[t - o] : 0u;
            __syncthreads();
            if (t < 256) hsc[t] += v;
            __syncthreads();
        }
        if (t < 256) {
            hsc[t] -= h0;                            // exclusive
            cur[t] = 0u;
            int c = bid * 256 + t;
            if (c <= N_NODES) off[c] = (int)(base + hsc[t]);
        }
        __syncthreads();
        for (unsigned i = t; i < sz; i += 512) {     // position + direct global scatter
            unsigned lo = rawA[i];
            unsigned d = (lo >> 16) & 255u;
            unsigned p = hsc[d] + atomicAdd(&cur[d], 1u);
            rw[base + p] = ((u64)rawB[i] << 32) | (lo & 0xFFFFu);
        }
    } else {
        // ---- phase B: deg for rows [b*256, +256) from row bucket, dis, xs ----
        int b = bid - NBKT;
        if (t < 256) facc[t] = 0.f;
        __syncthreads();
        unsigned szr = min(gcur[256 + b], (unsigned)CAP);
        for (unsigned i = t; i < szr; i += 512) {
            unsigned v = rslot[b * CAP + i];
            atomicAdd(&facc[v & 255u], __uint_as_float(v & 0xFFFFFF00u));
        }
        __syncthreads();
        if (t < 256) {
            float d = facc[t];
            float r = d > 0.f ? rsqrtf(d) : 0.f;
            facc[t] = r;
            int n = b * 256 + t;
            if (n < N_NODES) dis[n] = r;
        }
        __syncthreads();
        for (int idx = t; idx < 8192; idx += 512) {  // xs = dis*x (own region, no alias)
            int nl = idx >> 5, q = idx & 31;
            int n = b * 256 + nl;
            if (n < N_NODES) {
                float2 xv = ((const float2*)x)[n * 32 + q];
                float r = facc[nl];
                xs[n * 32 + q] = packbf2(r * xv.x, r * xv.y);
            }
        }
    }
}

// ---- prop: one wave per node; halves handle alternating edges ----
// mode 0: tx1 = -dis*sum(w*xs[row]); write abuf tx1 + t1s = dis*tx1
// mode 1: tx2 = 2*(-dis*sum(w*t1s[row])) - x(fp32); write abuf tx2
__global__ __launch_bounds__(256) void k_prop(
    const int* __restrict__ off, const u64* __restrict__ rw,
    const unsigned* __restrict__ xsrc, const float* __restrict__ dis,
    const float* __restrict__ xf, unsigned* __restrict__ abuf,
    unsigned* __restrict__ t1s, int mode) {
    int node = (blockIdx.x * 256 + threadIdx.x) >> 6;
    if (node >= N_NODES) return;
    int lane = threadIdx.x & 63, h = lane >> 5, q = lane & 31;
    int b = off[node], end = off[node + 1];
    float di = dis[node];
    float acc0 = 0.f, acc1 = 0.f;
    for (; b + 7 < end; b += 8) {
        u64 v0 = rw[b + h], v1 = rw[b + h + 2], v2 = rw[b + h + 4], v3 = rw[b + h + 6];
        unsigned r0 = (unsigned)v0 & 0xFFFFu, r1 = (unsigned)v1 & 0xFFFFu;
        unsigned r2 = (unsigned)v2 & 0xFFFFu, r3 = (unsigned)v3 & 0xFFFFu;
        float a0 = __uint_as_float((unsigned)(v0 >> 32));
        float a1 = __uint_as_float((unsigned)(v1 >> 32));
        float a2 = __uint_as_float((unsigned)(v2 >> 32));
        float a3 = __uint_as_float((unsigned)(v3 >> 32));
        unsigned u0 = xsrc[r0 * 32 + q], u1 = xsrc[r1 * 32 + q];
        unsigned u2 = xsrc[r2 * 32 + q], u3 = xsrc[r3 * 32 + q];
        acc0 += a0 * bflo(u0) + a1 * bflo(u1) + a2 * bflo(u2) + a3 * bflo(u3);
        acc1 += a0 * bfhi(u0) + a1 * bfhi(u1) + a2 * bfhi(u2) + a3 * bfhi(u3);
    }
    for (; b + 1 < end; b += 2) {
        u64 v = rw[b + h];
        unsigned r = (unsigned)v & 0xFFFFu;
        float a = __uint_as_float((unsigned)(v >> 32));
        unsigned u = xsrc[r * 32 + q];
        acc0 += a * bflo(u); acc1 += a * bfhi(u);
    }
    if (b < end && h == 0) {
        u64 v = rw[b];
        unsigned r = (unsigned)v & 0xFFFFu;
        float a = __uint_as_float((unsigned)(v >> 32));
        unsigned u = xsrc[r * 32 + q];
        acc0 += a * bflo(u); acc1 += a * bfhi(u);
    }
    acc0 += __shfl_xor(acc0, 32, 64);
    acc1 += __shfl_xor(acc1, 32, 64);
    if (h == 0) {
        float t0 = -di * acc0, t1v = -di * acc1;
        if (mode == 0) {
            abuf[node * 96 + 32 + q] = packbf2(t0, t1v);
            t1s[node * 32 + q] = packbf2(di * t0, di * t1v);
        } else {
            float2 xv = ((const float2*)xf)[node * 32 + q];
            abuf[node * 96 + 64 + q] = packbf2(2.f * t0 - xv.x, 2.f * t1v - xv.y);
        }
    }
}

// ---- MFMA GEMM [50000x192]@[192x128] + GRU combine + head ----
__global__ __launch_bounds__(256) void k_gemm(
    const ushort_t* __restrict__ ab, const ushort_t* __restrict__ pbuf,
    const float* __restrict__ bxz, const float* __restrict__ bhz,
    const float* __restrict__ bxh, const float* __restrict__ bhh,
    const float* __restrict__ Wlin, const float* __restrict__ blin,
    float2* __restrict__ out) {
    __shared__ ushort_t bsh[24576];
    int tid = threadIdx.x;
    {
        uint4* s4 = (uint4*)bsh;
        const uint4* g4 = (const uint4*)pbuf;
        for (int i = tid; i < 3072; i += 256) s4[i] = g4[i];
    }
    __syncthreads();

    int wave = tid >> 6, lane = tid & 63;
    int quad = lane >> 4, m = lane & 15;
    int arow = blockIdx.x * 64 + wave * 16 + m;
    const ushort_t* ap = ab + (size_t)arow * 192 + quad * 8;

    f32x4 acc[8];
#pragma unroll
    for (int c = 0; c < 8; ++c) acc[c] = (f32x4){0.f, 0.f, 0.f, 0.f};
#pragma unroll
    for (int s = 0; s < 6; ++s) {
        bf16x8 af = *(const bf16x8*)(ap + s * 32);
#pragma unroll
        for (int c = 0; c < 8; ++c) {
            bf16x8 bfr = *(const bf16x8*)(bsh + ((c * 6 + s) * 64 + lane) * 8);
            acc[c] = __builtin_amdgcn_mfma_f32_16x16x32_bf16(af, bfr, acc[c], 0, 0, 0);
        }
    }
    float bzv[4], bhv[4], wl0[4], wl1[4];
#pragma unroll
    for (int c = 0; c < 4; ++c) {
        int col = c * 16 + m;
        bzv[c] = bxz[col] + bhz[col];
        bhv[c] = bxh[col] + bhh[col];
        wl0[c] = Wlin[2 * col];
        wl1[c] = Wlin[2 * col + 1];
    }
    float bl0 = blin[0], bl1 = blin[1];
#pragma unroll
    for (int i = 0; i < 4; ++i) {
        float p0 = 0.f, p1 = 0.f;
#pragma unroll
        for (int c = 0; c < 4; ++c) {
            float z  = fsigmoid(acc[c][i] + bzv[c]);
            float ht = ftanh(acc[c + 4][i] + bhv[c]);
            float t  = ftanh((1.f - z) * ht);
            p0 += t * wl0[c];
            p1 += t * wl1[c];
        }
        for (int o = 1; o <= 8; o <<= 1) {
            p0 += __shfl_xor(p0, o, 64);
            p1 += __shfl_xor(p1, o, 64);
        }
        int g = blockIdx.x * 64 + wave * 16 + quad * 4 + i;
        if (m == 0 && g < N_NODES)
            out[g] = make_float2(fsigmoid(p0 + bl0), fsigmoid(p1 + bl1));
    }
}

extern "C" void kernel_launch(void* const* d_in, const int* in_sizes, int n_in,
                              void* d_out, int out_size, void* d_ws, size_t ws_size,
                              hipStream_t stream) {
    const float* x    = (const float*)d_in[0];
    const int*   ei   = (const int*)d_in[1];
    const float* ew   = (const float*)d_in[2];
    const float* Wxz  = (const float*)d_in[3];
    const float* bxz  = (const float*)d_in[4];
    const float* bhz  = (const float*)d_in[6];
    const float* Wxh  = (const float*)d_in[11];
    const float* bxh  = (const float*)d_in[12];
    const float* bhh  = (const float*)d_in[14];
    const float* Wlin = (const float*)d_in[15];
    const float* blin = (const float*)d_in[16];

    float*    ws    = (float*)d_ws;
    unsigned* gcur  = (unsigned*)(ws + GCUR_O);
    float*    dis   = ws + DIS_O;
    int*      off   = (int*)(ws + OFF_O);
    u64*      cslot = (u64*)(ws + CSLOT_O);
    unsigned* rslot = (unsigned*)(ws + RSLOT_O);
    u64*      rw    = (u64*)(ws + RW_O);
    unsigned* abuf  = (unsigned*)(ws + ABUF_O);
    ushort_t* pbuf  = (ushort_t*)(ws + PBUF_O);
    unsigned* xs    = (unsigned*)(ws + XS_O);    // own region (race fix)
    unsigned* t1s   = (unsigned*)(ws + T1S_O);   // aliases rslot (safe)

    hipMemsetAsync(d_ws, 0, 512 * 4, stream);    // just the cursors

    k1<<<NB1 + 98 + 1, 512, 0, stream>>>(ei, ew, x, Wxz, Wxh, gcur, cslot, rslot, abuf, pbuf);
    k2<<<NBKT * 2, 512, 0, stream>>>(x, gcur, cslot, rslot, dis, off, rw, xs);
    k_prop<<<12500, 256, 0, stream>>>(off, rw, xs, dis, x, abuf, t1s, 0);
    k_prop<<<12500, 256, 0, stream>>>(off, rw, t1s, dis, x, abuf, abuf, 1);
    k_gemm<<<782, 256, 0, stream>>>((const ushort_t*)abuf, pbuf, bxz, bhz, bxh, bhh,
                                    Wlin, blin, (float2*)d_out);
}